// Round 1
// baseline (475.561 us; speedup 1.0000x reference)
//
#include <hip/hip_runtime.h>

// CustomFourierLayer: out[b,o] = sum_{i,k} coef[o,i,k] * f_k(x[b,i])
// f = [sin(1x..16x), cos(1x..16x), 1]  -> GEMM  out = V * C^T
// B=4096, I=1024, O=1024, 33 features, K' = 33792.

#define B_ROWS 4096
#define O_COLS 1024
#define I_DIM  1024
#define NF     33
#define NIB    16              // i-blocks of 64
#define KPRIME (NIB * NF * 64) // 33792
#define CW_ELEMS ((size_t)O_COLS * (size_t)KPRIME)

typedef _Float16 half8 __attribute__((ext_vector_type(8)));
typedef float float4v __attribute__((ext_vector_type(4)));

union H8 { half8 v; _Float16 h[8]; };

__device__ __forceinline__ void gload16(const void* g, void* l) {
  typedef const __attribute__((address_space(1))) unsigned int GU;
  typedef __attribute__((address_space(3))) unsigned int LU;
  __builtin_amdgcn_global_load_lds((GU*)g, (LU*)l, 16, 0, 0);
}

// source k index in coef's [sin1..16 | cos1..16 | 1] layout for reordered
// feature f in [s1,c1,s2,c2,...,s16,c16,1]
__device__ __forceinline__ int ksrc_of(int f) {
  return (f == 32) ? 32 : ((f >> 1) + ((f & 1) ? 16 : 0));
}

// ---------------------------------------------------------------------------
// Pre-pass: coef f32 [o][i][k] -> Cw f16 [o][iblk][f][j], f16, with within-row
// 16B-chunk XOR swizzle by (o&7) so the GEMM can global_load_lds linearly and
// ds_read conflict-free.
// ---------------------------------------------------------------------------
__global__ __launch_bounds__(64)
void convert_coef(const float* __restrict__ coef, _Float16* __restrict__ Cw) {
  const int bid = blockIdx.x;
  const int o = bid >> 4;        // 0..1023
  const int ib = bid & 15;       // 0..15
  const int j = threadIdx.x;     // 0..63
  const int i = ib * 64 + j;

  const float* src = coef + (size_t)o * (I_DIM * NF) + (size_t)i * NF;
  float r[NF];
#pragma unroll
  for (int kk = 0; kk < NF; ++kk) r[kk] = src[kk];

  const int c = j >> 3, e = j & 7;
  const int jswz = ((c ^ (o & 7)) << 3) + e;   // swizzled position within 64
  _Float16* dst = Cw + (size_t)o * KPRIME + (size_t)ib * (NF * 64) + jswz;
#pragma unroll
  for (int f = 0; f < NF; ++f) {
    dst[f * 64] = (_Float16)r[ksrc_of(f)];     // RNE convert
  }
}

// ---------------------------------------------------------------------------
// Fused GEMM: BM=128, BN=128, BK=64, 512 threads (8 waves, 4x2 of 32x64).
// A-tile generated in-register via sin/cos angle-addition recurrence.
// ---------------------------------------------------------------------------
template <bool USE_WS>
__global__ __launch_bounds__(512, 2)
void fourier_gemm(const float* __restrict__ x, const float* __restrict__ coef,
                  const _Float16* __restrict__ Cw, float* __restrict__ out) {
  __shared__ _Float16 As[128 * 64];
  __shared__ _Float16 Bs[128 * 64];

  const int tid = threadIdx.x;
  const int lane = tid & 63;
  const int wave = tid >> 6;        // 0..7
  const int wr = wave >> 1;         // 0..3 : rows wr*32..+32
  const int wc = wave & 1;          // 0..1 : cols wc*64..+64

  const int bid = blockIdx.x;       // 256 blocks
  const int o0 = (bid & 7) * 128;
  const int m0 = (bid >> 3) * 128;

  // A-gen: thread owns 2 groups of 8 cells: (rowA, cch) and (rowA+64, cch)
  const int rowA = tid >> 3;        // 0..63
  const int rowB = rowA + 64;
  const int cch = tid & 7;          // logical 16B chunk (8 f16)
  const int cswz = cch ^ (rowA & 7); // rowB&7 == rowA&7

  // B staging mapping (chunk q = tid and tid+512)
  const int n1 = tid >> 3;          // 0..63
  const int n2 = n1 + 64;
  const int c1q = tid & 7;

  float4v acc[2][4] = {};

  float s1a[8], c1a[8], sa[8], ca[8];
  float s1b[8], c1b[8], sb[8], cb[8];

  const int r16 = lane & 15;
  const int kq = lane >> 4;

  for (int ib = 0; ib < NIB; ++ib) {
    // load x for owned cells, compute sin/cos base, init recurrence
    {
      const float* xa = x + (size_t)(m0 + rowA) * I_DIM + ib * 64 + cch * 8;
      const float* xb = x + (size_t)(m0 + rowB) * I_DIM + ib * 64 + cch * 8;
      float xva[8], xvb[8];
      *(float4*)&xva[0] = *(const float4*)(xa);
      *(float4*)&xva[4] = *(const float4*)(xa + 4);
      *(float4*)&xvb[0] = *(const float4*)(xb);
      *(float4*)&xvb[4] = *(const float4*)(xb + 4);
#pragma unroll
      for (int e = 0; e < 8; ++e) {
        __sincosf(xva[e], &s1a[e], &c1a[e]);
        sa[e] = s1a[e]; ca[e] = c1a[e];
        __sincosf(xvb[e], &s1b[e], &c1b[e]);
        sb[e] = s1b[e]; cb[e] = c1b[e];
      }
    }

#pragma unroll 1
    for (int f = 0; f < NF; ++f) {
      // ---- emit values for this feature into regs (RNE f16) ----
      H8 ha, hb;
      if (f == 32) {
#pragma unroll
        for (int e = 0; e < 8; ++e) { ha.h[e] = (_Float16)1.0f; hb.h[e] = (_Float16)1.0f; }
      } else if ((f & 1) == 0) {
#pragma unroll
        for (int e = 0; e < 8; ++e) { ha.h[e] = (_Float16)sa[e]; hb.h[e] = (_Float16)sb[e]; }
      } else {
#pragma unroll
        for (int e = 0; e < 8; ++e) { ha.h[e] = (_Float16)ca[e]; hb.h[e] = (_Float16)cb[e]; }
      }

      __syncthreads();   // previous step's frag reads complete

      // ---- stage A (swizzled ds_write from regs) ----
      *(half8*)&As[rowA * 64 + cswz * 8] = ha.v;
      *(half8*)&As[rowB * 64 + cswz * 8] = hb.v;

      // ---- stage B ----
      if (USE_WS) {
        // Cw stored pre-swizzled: linear copy via global_load_lds width=16
        const _Float16* sp = Cw + (size_t)(o0 + n1) * KPRIME
                               + (size_t)ib * (NF * 64) + f * 64 + c1q * 8;
        gload16(sp, (char*)Bs + wave * 1024);
        gload16(sp + (size_t)64 * KPRIME, (char*)Bs + 8192 + wave * 1024);
      } else {
        const int ks = ksrc_of(f);
        H8 b1, b2;
#pragma unroll
        for (int e = 0; e < 8; ++e) {
          const size_t ii = (size_t)(ib * 64 + c1q * 8 + e) * NF + ks;
          b1.h[e] = (_Float16)coef[(size_t)(o0 + n1) * (I_DIM * NF) + ii];
          b2.h[e] = (_Float16)coef[(size_t)(o0 + n2) * (I_DIM * NF) + ii];
        }
        const int cs = (c1q ^ (n1 & 7)) << 3;  // n2&7 == n1&7
        *(half8*)&Bs[n1 * 64 + cs] = b1.v;
        *(half8*)&Bs[n2 * 64 + cs] = b2.v;
      }

      // ---- advance recurrence (after emitting cos_k) ----
      if (f & 1) {
#pragma unroll
        for (int e = 0; e < 8; ++e) {
          float ns = sa[e] * c1a[e] + ca[e] * s1a[e];
          ca[e] = ca[e] * c1a[e] - sa[e] * s1a[e];
          sa[e] = ns;
          float nsb = sb[e] * c1b[e] + cb[e] * s1b[e];
          cb[e] = cb[e] * c1b[e] - sb[e] * s1b[e];
          sb[e] = nsb;
        }
      }

      __syncthreads();   // compiler drains vmcnt/lgkmcnt before barrier

      // ---- MFMA: 2 k-chunks x (2 A-frags x 4 B-frags) ----
#pragma unroll
      for (int ksu = 0; ksu < 2; ++ksu) {
        const int ch = ((ksu << 2) + kq) ^ (r16 & 7);
        half8 af[2], bf[4];
#pragma unroll
        for (int fr = 0; fr < 2; ++fr)
          af[fr] = *(const half8*)&As[(wr * 32 + fr * 16 + r16) * 64 + ch * 8];
#pragma unroll
        for (int fc = 0; fc < 4; ++fc)
          bf[fc] = *(const half8*)&Bs[(wc * 64 + fc * 16 + r16) * 64 + ch * 8];
#pragma unroll
        for (int fr = 0; fr < 2; ++fr)
#pragma unroll
          for (int fc = 0; fc < 4; ++fc)
            acc[fr][fc] = __builtin_amdgcn_mfma_f32_16x16x32_f16(
                af[fr], bf[fc], acc[fr][fc], 0, 0, 0);
      }
    }
  }

  // ---- epilogue: C/D layout col=lane&15, row=(lane>>4)*4+reg (m89) ----
#pragma unroll
  for (int fr = 0; fr < 2; ++fr)
#pragma unroll
    for (int fc = 0; fc < 4; ++fc)
#pragma unroll
      for (int r = 0; r < 4; ++r) {
        const int row = m0 + wr * 32 + fr * 16 + kq * 4 + r;
        const int col = o0 + wc * 64 + fc * 16 + r16;
        out[(size_t)row * O_COLS + col] = acc[fr][fc][r];
      }
}

extern "C" void kernel_launch(void* const* d_in, const int* in_sizes, int n_in,
                              void* d_out, int out_size, void* d_ws, size_t ws_size,
                              hipStream_t stream) {
  const float* x = (const float*)d_in[0];
  const float* coef = (const float*)d_in[1];
  float* out = (float*)d_out;
  _Float16* Cw = (_Float16*)d_ws;

  const bool use_ws = ws_size >= CW_ELEMS * sizeof(_Float16);

  if (use_ws) {
    convert_coef<<<dim3(O_COLS * NIB), dim3(64), 0, stream>>>(coef, Cw);
    fourier_gemm<true><<<dim3(256), dim3(512), 0, stream>>>(x, coef, Cw, out);
  } else {
    fourier_gemm<false><<<dim3(256), dim3(512), 0, stream>>>(x, coef, Cw, out);
  }
}

// Round 2
// 469.602 us; speedup vs baseline: 1.0127x; 1.0127x over previous
//
#include <hip/hip_runtime.h>

// CustomFourierLayer: out[b,o] = sum_{i,k} coef[o,i,k] * f_k(x[b,i])
// f = [sin(1x..16x), cos(1x..16x), 1]  -> GEMM  out = V * C^T
// B=4096, I=1024, O=1024, 33 features, K' = 33792.
//
// R2: single-barrier double-buffered pipeline (As/Bs x2, 64KB LDS).
// B gloads for step s+1 issued at top of step s -> full MFMA phase of slack
// before the compiler's vmcnt(0) drain at the barrier.

#define B_ROWS 4096
#define O_COLS 1024
#define I_DIM  1024
#define NF     33
#define NIB    16              // i-blocks of 64
#define KPRIME (NIB * NF * 64) // 33792
#define CW_ELEMS ((size_t)O_COLS * (size_t)KPRIME)

typedef _Float16 half8 __attribute__((ext_vector_type(8)));
typedef float float4v __attribute__((ext_vector_type(4)));

union H8 { half8 v; _Float16 h[8]; };

__device__ __forceinline__ void gload16(const void* g, void* l) {
  typedef const __attribute__((address_space(1))) unsigned int GU;
  typedef __attribute__((address_space(3))) unsigned int LU;
  __builtin_amdgcn_global_load_lds((GU*)g, (LU*)l, 16, 0, 0);
}

// source k index in coef's [sin1..16 | cos1..16 | 1] layout for reordered
// feature f in [s1,c1,s2,c2,...,s16,c16,1]
__device__ __forceinline__ int ksrc_of(int f) {
  return (f == 32) ? 32 : ((f >> 1) + ((f & 1) ? 16 : 0));
}

// ---------------------------------------------------------------------------
// Pre-pass: coef f32 [o][i][k] -> Cw f16 [o][iblk][f][j], with within-row
// 16B-chunk XOR swizzle by (o&7) so the GEMM stages with linear
// global_load_lds and ds_reads are bank-conflict-free.
// ---------------------------------------------------------------------------
__global__ __launch_bounds__(64)
void convert_coef(const float* __restrict__ coef, _Float16* __restrict__ Cw) {
  const int bid = blockIdx.x;
  const int o = bid >> 4;        // 0..1023
  const int ib = bid & 15;       // 0..15
  const int j = threadIdx.x;     // 0..63
  const int i = ib * 64 + j;

  const float* src = coef + (size_t)o * (I_DIM * NF) + (size_t)i * NF;
  float r[NF];
#pragma unroll
  for (int kk = 0; kk < NF; ++kk) r[kk] = src[kk];

  const int c = j >> 3, e = j & 7;
  const int jswz = ((c ^ (o & 7)) << 3) + e;   // swizzled position within 64
  _Float16* dst = Cw + (size_t)o * KPRIME + (size_t)ib * (NF * 64) + jswz;
#pragma unroll
  for (int f = 0; f < NF; ++f) {
    dst[f * 64] = (_Float16)r[ksrc_of(f)];     // RNE convert
  }
}

// ---------------------------------------------------------------------------
// Fused GEMM: BM=128, BN=128, BK=64 (one feature per step), 512 threads
// (8 waves, 4x2 of 32x64). A generated in-register via angle-addition
// recurrence; 1 barrier/step, double-buffered LDS.
// ---------------------------------------------------------------------------
template <bool USE_WS>
__global__ __launch_bounds__(512, 2)
void fourier_gemm(const float* __restrict__ x, const float* __restrict__ coef,
                  const _Float16* __restrict__ Cw, float* __restrict__ out) {
  __shared__ _Float16 As[2][128 * 64];
  __shared__ _Float16 Bs[2][128 * 64];

  const int tid = threadIdx.x;
  const int lane = tid & 63;
  const int wave = tid >> 6;        // 0..7
  const int wr = wave >> 1;         // 0..3 : rows wr*32..+32
  const int wc = wave & 1;          // 0..1 : cols wc*64..+64

  const int bid = blockIdx.x;       // 256 blocks; bid&7 = o-slice == XCD id
  const int o0 = (bid & 7) * 128;
  const int m0 = (bid >> 3) * 128;

  // A-gen: thread owns rows (rowA, rowA+64), 16B chunk cch
  const int rowA = tid >> 3;        // 0..63
  const int cch = tid & 7;
  const int cswz = cch ^ (rowA & 7);

  // B staging mapping
  const int n1 = tid >> 3;          // 0..63
  const int c1q = tid & 7;

  const int r16 = lane & 15;
  const int kq = lane >> 4;

  float4v acc[2][4] = {};

  float s1a[8], c1a[8], sa[8], ca[8];
  float s1b[8], c1b[8], sb[8], cb[8];

  const float* xa_base = x + (size_t)(m0 + rowA) * I_DIM + cch * 8;
  const float* xb_base = xa_base + (size_t)64 * I_DIM;

  auto init_ib = [&](int ib) {
    float xva[8], xvb[8];
    *(float4*)&xva[0] = *(const float4*)(xa_base + ib * 64);
    *(float4*)&xva[4] = *(const float4*)(xa_base + ib * 64 + 4);
    *(float4*)&xvb[0] = *(const float4*)(xb_base + ib * 64);
    *(float4*)&xvb[4] = *(const float4*)(xb_base + ib * 64 + 4);
#pragma unroll
    for (int e = 0; e < 8; ++e) {
      __sincosf(xva[e], &s1a[e], &c1a[e]);
      sa[e] = s1a[e]; ca[e] = c1a[e];
      __sincosf(xvb[e], &s1b[e], &c1b[e]);
      sb[e] = s1b[e]; cb[e] = c1b[e];
    }
  };

  auto stage_A = [&](int f1, int pn) {
    H8 ha, hb;
    if (f1 == NF - 1) {
#pragma unroll
      for (int e = 0; e < 8; ++e) { ha.h[e] = (_Float16)1.0f; hb.h[e] = (_Float16)1.0f; }
    } else if ((f1 & 1) == 0) {
#pragma unroll
      for (int e = 0; e < 8; ++e) { ha.h[e] = (_Float16)sa[e]; hb.h[e] = (_Float16)sb[e]; }
    } else {
#pragma unroll
      for (int e = 0; e < 8; ++e) { ha.h[e] = (_Float16)ca[e]; hb.h[e] = (_Float16)cb[e]; }
    }
    *(half8*)&As[pn][rowA * 64 + cswz * 8] = ha.v;
    *(half8*)&As[pn][(rowA + 64) * 64 + cswz * 8] = hb.v;
    if ((f1 & 1) && f1 < NF - 1) {   // advance recurrence after emitting cos_k
#pragma unroll
      for (int e = 0; e < 8; ++e) {
        float ns = sa[e] * c1a[e] + ca[e] * s1a[e];
        ca[e] = ca[e] * c1a[e] - sa[e] * s1a[e];
        sa[e] = ns;
        float nsb = sb[e] * c1b[e] + cb[e] * s1b[e];
        cb[e] = cb[e] * c1b[e] - sb[e] * s1b[e];
        sb[e] = nsb;
      }
    }
  };

  auto stage_B = [&](int ib1, int f1, int pn) {
    if (USE_WS) {
      const _Float16* sp = Cw + (size_t)(o0 + n1) * KPRIME
                             + (size_t)ib1 * (NF * 64) + f1 * 64 + c1q * 8;
      gload16(sp, (char*)&Bs[pn][0] + wave * 1024);
      gload16(sp + (size_t)64 * KPRIME, (char*)&Bs[pn][0] + 8192 + wave * 1024);
    } else {
      const int ks = ksrc_of(f1);
      H8 b1, b2;
#pragma unroll
      for (int e = 0; e < 8; ++e) {
        const size_t ii = (size_t)(ib1 * 64 + c1q * 8 + e) * NF + ks;
        b1.h[e] = (_Float16)coef[(size_t)(o0 + n1) * (I_DIM * NF) + ii];
        b2.h[e] = (_Float16)coef[(size_t)(o0 + n1 + 64) * (I_DIM * NF) + ii];
      }
      const int cs = (c1q ^ (n1 & 7)) << 3;
      *(half8*)&Bs[pn][n1 * 64 + cs] = b1.v;
      *(half8*)&Bs[pn][(n1 + 64) * 64 + cs] = b2.v;
    }
  };

  // ---- prologue: stage step 0 (ib=0, f=0) into buffer 0 ----
  init_ib(0);
  stage_B(0, 0, 0);
  stage_A(0, 0);
  __syncthreads();

  int p = 0;
#pragma unroll 1
  for (int ib = 0; ib < NIB; ++ib) {
#pragma unroll 1
    for (int f = 0; f < NF; ++f) {
      // ---- stage step s+1 into buffer p^1 (gloads first: longest latency) ----
      if (f < NF - 1) {
        stage_B(ib, f + 1, p ^ 1);
        stage_A(f + 1, p ^ 1);
      } else if (ib < NIB - 1) {
        stage_B(ib + 1, 0, p ^ 1);
        init_ib(ib + 1);
        stage_A(0, p ^ 1);
      }

      // ---- compute step s from buffer p ----
#pragma unroll
      for (int ksu = 0; ksu < 2; ++ksu) {
        const int ch = ((ksu << 2) + kq) ^ (r16 & 7);
        half8 af[2], bf[4];
#pragma unroll
        for (int fr = 0; fr < 2; ++fr)
          af[fr] = *(const half8*)&As[p][(wr * 32 + fr * 16 + r16) * 64 + ch * 8];
#pragma unroll
        for (int fc = 0; fc < 4; ++fc)
          bf[fc] = *(const half8*)&Bs[p][(wc * 64 + fc * 16 + r16) * 64 + ch * 8];
#pragma unroll
        for (int fr = 0; fr < 2; ++fr)
#pragma unroll
          for (int fc = 0; fc < 4; ++fc)
            acc[fr][fc] = __builtin_amdgcn_mfma_f32_16x16x32_f16(
                af[fr], bf[fc], acc[fr][fc], 0, 0, 0);
      }

      __syncthreads();   // one barrier/step: drains A-writes + B-gloads (with
                         // a full ds_read+MFMA phase of slack) and frag reads
      p ^= 1;
    }
  }

  // ---- epilogue: C/D layout col=lane&15, row=(lane>>4)*4+reg (m89) ----
#pragma unroll
  for (int fr = 0; fr < 2; ++fr)
#pragma unroll
    for (int fc = 0; fc < 4; ++fc)
#pragma unroll
      for (int r = 0; r < 4; ++r) {
        const int row = m0 + wr * 32 + fr * 16 + kq * 4 + r;
        const int col = o0 + wc * 64 + fc * 16 + r16;
        out[(size_t)row * O_COLS + col] = acc[fr][fc][r];
      }
}

extern "C" void kernel_launch(void* const* d_in, const int* in_sizes, int n_in,
                              void* d_out, int out_size, void* d_ws, size_t ws_size,
                              hipStream_t stream) {
  const float* x = (const float*)d_in[0];
  const float* coef = (const float*)d_in[1];
  float* out = (float*)d_out;
  _Float16* Cw = (_Float16*)d_ws;

  const bool use_ws = ws_size >= CW_ELEMS * sizeof(_Float16);

  if (use_ws) {
    convert_coef<<<dim3(O_COLS * NIB), dim3(64), 0, stream>>>(coef, Cw);
    fourier_gemm<true><<<dim3(256), dim3(512), 0, stream>>>(x, coef, Cw, out);
  } else {
    fourier_gemm<false><<<dim3(256), dim3(512), 0, stream>>>(x, coef, Cw, out);
  }
}

// Round 3
// 409.452 us; speedup vs baseline: 1.1615x; 1.1469x over previous
//
#include <hip/hip_runtime.h>

// CustomFourierLayer: out[b,o] = sum_{i,k} coef[o,i,k] * f_k(x[b,i])
// f = [sin(1x..16x), cos(1x..16x), 1]  -> GEMM  out = V * C^T (+ bias)
// B=4096, I=O=1024. R3: revert to lean 2-barrier structure (r1), add
// split-K x2 -> 2 blocks/CU (m114 overlap), bias folded out of GEMM.

#define O_COLS 1024
#define I_DIM  1024
#define NFW    32                       // sin/cos features in ws-GEMM
#define NF33   33                       // original coef feature count
#define NIB    16                       // i-blocks of 64
#define KPW    (NIB * NFW * 64)         // 32768 per o-row in Cw
#define CW_BYTES ((size_t)O_COLS * KPW * 2)

typedef _Float16 half8 __attribute__((ext_vector_type(8)));
typedef float float4v __attribute__((ext_vector_type(4)));
union H8 { half8 v; _Float16 h[8]; };

__device__ __forceinline__ void gload16(const void* g, void* l) {
  typedef const __attribute__((address_space(1))) unsigned int GU;
  typedef __attribute__((address_space(3))) unsigned int LU;
  __builtin_amdgcn_global_load_lds((GU*)g, (LU*)l, 16, 0, 0);
}

// source k in coef's [sin1..16 | cos1..16 | 1] layout for reordered feature f
__device__ __forceinline__ int ksrc_of(int f) {
  return (f >= 32) ? 32 : ((f >> 1) + ((f & 1) ? 16 : 0));
}

// ---------------------------------------------------------------------------
// Pre-pass: coef f32 [o][i][k] -> Cw f16 [o][ib][f0..31][j] (16B-chunk XOR
// swizzle by o&7), plus bias[o] = sum_i coef[o][i][32] via wave-reduce+atomic.
// ---------------------------------------------------------------------------
__global__ __launch_bounds__(64)
void convert_coef(const float* __restrict__ coef, _Float16* __restrict__ Cw,
                  float* __restrict__ bias) {
  const int bid = blockIdx.x;
  const int o = bid >> 4;        // 0..1023
  const int ib = bid & 15;       // 0..15
  const int j = threadIdx.x;     // 0..63
  const int i = ib * 64 + j;

  const float* src = coef + (size_t)o * (I_DIM * NF33) + (size_t)i * NF33;
  float r[NF33];
#pragma unroll
  for (int kk = 0; kk < NF33; ++kk) r[kk] = src[kk];

  const int c = j >> 3, e = j & 7;
  const int jswz = ((c ^ (o & 7)) << 3) + e;   // swizzled position within 64
  _Float16* dst = Cw + (size_t)o * KPW + (size_t)ib * (NFW * 64) + jswz;
#pragma unroll
  for (int f = 0; f < NFW; ++f) {
    dst[f * 64] = (_Float16)r[ksrc_of(f)];     // RNE convert
  }

  // bias partial: sum of r[32] over this block's 64 i's
  float bsum = r[32];
#pragma unroll
  for (int off = 32; off > 0; off >>= 1) bsum += __shfl_down(bsum, off);
  if (j == 0) atomicAdd(&bias[o], bsum);
}

// ---------------------------------------------------------------------------
// Fused GEMM: BM=128, BN=128, BK=64 (one feature per step), 512 threads
// (8 waves, 4x2 of 32x64). Split-K x2 (kb by i-block halves), atomicAdd
// epilogue into zeroed out. A generated in-register (angle-addition
// recurrence), lean 2-barrier step. 32KB LDS -> 2 blocks/CU.
// ---------------------------------------------------------------------------
template <bool USE_WS>
__global__ __launch_bounds__(512, 4)
void fourier_gemm(const float* __restrict__ x, const float* __restrict__ coef,
                  const _Float16* __restrict__ Cw, const float* __restrict__ bias,
                  float* __restrict__ out) {
  __shared__ _Float16 As[128 * 64];
  __shared__ _Float16 Bs[128 * 64];

  const int tid = threadIdx.x;
  const int lane = tid & 63;
  const int wave = tid >> 6;        // 0..7
  const int wr = wave >> 1;         // 0..3 : rows wr*32..+32
  const int wc = wave & 1;          // 0..1 : cols wc*64..+64

  const int bid = blockIdx.x;       // 512 blocks; bid&7 = o-slice == XCD id
  const int o0 = (bid & 7) * 128;
  const int kb = (bid >> 3) & 1;    // split-K half
  const int m0 = (bid >> 4) * 128;

  const int rowA = tid >> 3;        // 0..63
  const int cch = tid & 7;
  const int cswz = cch ^ (rowA & 7);

  const int n1 = tid >> 3;          // B staging row
  const int c1q = tid & 7;

  const int r16 = lane & 15;
  const int kq = lane >> 4;

  const int NFG = USE_WS ? NFW : NF33;

  float4v acc[2][4];
#pragma unroll
  for (int fr = 0; fr < 2; ++fr)
#pragma unroll
    for (int fc = 0; fc < 4; ++fc)
      acc[fr][fc] = (float4v){0.f, 0.f, 0.f, 0.f};
  if (USE_WS && kb == 0) {
#pragma unroll
    for (int fc = 0; fc < 4; ++fc) {
      const float bv = bias[o0 + wc * 64 + fc * 16 + r16];
      acc[0][fc] = (float4v){bv, bv, bv, bv};
      acc[1][fc] = acc[0][fc];
    }
  }

  float s1a[8], c1a[8], sa[8], ca[8];
  float s1b[8], c1b[8], sb[8], cb[8];

  const float* xa_base = x + (size_t)(m0 + rowA) * I_DIM + (size_t)kb * 512 + cch * 8;
  const float* xb_base = xa_base + (size_t)64 * I_DIM;
  // running B pointer (USE_WS): advance by 64 per step
  const _Float16* spB = Cw + (size_t)(o0 + n1) * KPW + (size_t)kb * 8 * (NFW * 64) + c1q * 8;

#pragma unroll 1
  for (int ib2 = 0; ib2 < 8; ++ib2) {
    // ---- per-i-block init: sincos base + recurrence state ----
    {
      const float* xa = xa_base + ib2 * 64;
      const float* xb = xb_base + ib2 * 64;
      float xva[8], xvb[8];
      *(float4*)&xva[0] = *(const float4*)(xa);
      *(float4*)&xva[4] = *(const float4*)(xa + 4);
      *(float4*)&xvb[0] = *(const float4*)(xb);
      *(float4*)&xvb[4] = *(const float4*)(xb + 4);
#pragma unroll
      for (int e = 0; e < 8; ++e) {
        __sincosf(xva[e], &s1a[e], &c1a[e]);
        sa[e] = s1a[e]; ca[e] = c1a[e];
        __sincosf(xvb[e], &s1b[e], &c1b[e]);
        sb[e] = s1b[e]; cb[e] = c1b[e];
      }
    }

#pragma unroll 2
    for (int f = 0; f < NFG; ++f) {
      // ---- emit this feature's A values (RNE f16) ----
      H8 ha, hb;
      if (!USE_WS && f == 32) {
#pragma unroll
        for (int e = 0; e < 8; ++e) { ha.h[e] = (_Float16)1.0f; hb.h[e] = (_Float16)1.0f; }
      } else if ((f & 1) == 0) {
#pragma unroll
        for (int e = 0; e < 8; ++e) { ha.h[e] = (_Float16)sa[e]; hb.h[e] = (_Float16)sb[e]; }
      } else {
#pragma unroll
        for (int e = 0; e < 8; ++e) { ha.h[e] = (_Float16)ca[e]; hb.h[e] = (_Float16)cb[e]; }
      }

      __syncthreads();   // previous step's frag reads complete

      // ---- stage B first (longest latency) ----
      if (USE_WS) {
        gload16(spB, (char*)Bs + wave * 1024);
        gload16(spB + (size_t)64 * KPW, (char*)Bs + 8192 + wave * 1024);
        spB += 64;
      } else {
        const int ks = ksrc_of(f);
        const int ibg = kb * 8 + ib2;
        H8 b1, b2;
#pragma unroll
        for (int e = 0; e < 8; ++e) {
          const size_t ii = (size_t)(ibg * 64 + c1q * 8 + e) * NF33 + ks;
          b1.h[e] = (_Float16)coef[(size_t)(o0 + n1) * (I_DIM * NF33) + ii];
          b2.h[e] = (_Float16)coef[(size_t)(o0 + n1 + 64) * (I_DIM * NF33) + ii];
        }
        const int cs = (c1q ^ (n1 & 7)) << 3;
        *(half8*)&Bs[n1 * 64 + cs] = b1.v;
        *(half8*)&Bs[(n1 + 64) * 64 + cs] = b2.v;
      }

      // ---- stage A (swizzled ds_write from regs) ----
      *(half8*)&As[rowA * 64 + cswz * 8] = ha.v;
      *(half8*)&As[(rowA + 64) * 64 + cswz * 8] = hb.v;

      // ---- advance recurrence (after emitting cos_k, if a sin follows) ----
      if ((f & 1) && (f + 2 < NFG)) {
#pragma unroll
        for (int e = 0; e < 8; ++e) {
          float ns = sa[e] * c1a[e] + ca[e] * s1a[e];
          ca[e] = ca[e] * c1a[e] - sa[e] * s1a[e];
          sa[e] = ns;
          float nsb = sb[e] * c1b[e] + cb[e] * s1b[e];
          cb[e] = cb[e] * c1b[e] - sb[e] * s1b[e];
          sb[e] = nsb;
        }
      }

      __syncthreads();   // staging visible (vmcnt/lgkmcnt drained here)

      // ---- MFMA: 2 k-chunks x (2 A-frags x 4 B-frags) ----
#pragma unroll
      for (int ksu = 0; ksu < 2; ++ksu) {
        const int ch = ((ksu << 2) + kq) ^ (r16 & 7);
        half8 af[2], bf[4];
#pragma unroll
        for (int fr = 0; fr < 2; ++fr)
          af[fr] = *(const half8*)&As[(wr * 32 + fr * 16 + r16) * 64 + ch * 8];
#pragma unroll
        for (int fc = 0; fc < 4; ++fc)
          bf[fc] = *(const half8*)&Bs[(wc * 64 + fc * 16 + r16) * 64 + ch * 8];
#pragma unroll
        for (int fr = 0; fr < 2; ++fr)
#pragma unroll
          for (int fc = 0; fc < 4; ++fc)
            acc[fr][fc] = __builtin_amdgcn_mfma_f32_16x16x32_f16(
                af[fr], bf[fc], acc[fr][fc], 0, 0, 0);
      }
    }
  }

  // ---- epilogue: atomicAdd into zeroed out (2 split-K writers per element) ----
#pragma unroll
  for (int fr = 0; fr < 2; ++fr)
#pragma unroll
    for (int fc = 0; fc < 4; ++fc)
#pragma unroll
      for (int r = 0; r < 4; ++r) {
        const int row = m0 + wr * 32 + fr * 16 + kq * 4 + r;
        const int col = o0 + wc * 64 + fc * 16 + r16;
        atomicAdd(&out[(size_t)row * O_COLS + col], acc[fr][fc][r]);
      }
}

extern "C" void kernel_launch(void* const* d_in, const int* in_sizes, int n_in,
                              void* d_out, int out_size, void* d_ws, size_t ws_size,
                              hipStream_t stream) {
  const float* x = (const float*)d_in[0];
  const float* coef = (const float*)d_in[1];
  float* out = (float*)d_out;

  const bool use_ws = ws_size >= CW_BYTES + O_COLS * sizeof(float);

  hipMemsetAsync(d_out, 0, (size_t)4096 * O_COLS * sizeof(float), stream);

  if (use_ws) {
    _Float16* Cw = (_Float16*)d_ws;
    float* bias = (float*)((char*)d_ws + CW_BYTES);
    hipMemsetAsync(bias, 0, O_COLS * sizeof(float), stream);
    convert_coef<<<dim3(O_COLS * NIB), dim3(64), 0, stream>>>(coef, Cw, bias);
    fourier_gemm<true><<<dim3(512), dim3(512), 0, stream>>>(x, coef, Cw, bias, out);
  } else {
    fourier_gemm<false><<<dim3(512), dim3(512), 0, stream>>>(x, coef, nullptr, nullptr, out);
  }
}